// Round 7
// baseline (369.365 us; speedup 1.0000x reference)
//
#include <hip/hip_runtime.h>

#define EMB   1024
#define HEADS 16
#define HDIM  64
#define BATCH 2
#define SEQ   2048
#define MROWS (BATCH*SEQ)   // 4096
#define STR   40            // qkv/oproj LDS k-stride in u16: 80 B
#define QSCALE 0.1803368801111204f   // 0.125 * log2(e): Q pre-scale -> exp2 softmax

typedef __attribute__((ext_vector_type(8))) short bf16x8;   // 8 bf16 (4 VGPRs)
typedef __attribute__((ext_vector_type(4))) float f32x4;    // 16x16 MFMA C/D
typedef __attribute__((ext_vector_type(16))) float f32x16;  // 32x32 MFMA C/D
typedef unsigned short u16;

__device__ __forceinline__ u16 f2bf(float f) {              // round-to-nearest-even
    unsigned u = __float_as_uint(f);
    u += 0x7fffu + ((u >> 16) & 1u);
    return (u16)(u >> 16);
}
__device__ __forceinline__ float bf2f(u16 h) {
    return __uint_as_float((unsigned)h << 16);
}
__device__ __forceinline__ float fast_exp2(float x) {
#if __has_builtin(__builtin_amdgcn_exp2f)
    return __builtin_amdgcn_exp2f(x);
#else
    return __expf(x * 0.6931471805599453f);
#endif
}
// pack two floats -> two truncated bf16 in one v_perm_b32 (lo in [15:0])
__device__ __forceinline__ unsigned pk_trunc(float lo, float hi) {
    return __builtin_amdgcn_perm(__float_as_uint(hi), __float_as_uint(lo),
                                 0x07060302u);
}

// ---------------------------------------------------------------------------
// prep1: fused  [bx<2048] X->Xh/Xl split | [bx<3072] Wq/Wk transpose+hi/lo
//        | [else] Wv transpose->bf16 (Wvt lives in d_out scratch).
// ---------------------------------------------------------------------------
__global__ __launch_bounds__(256)
void prep1(const float* __restrict__ X, const float* __restrict__ Wq,
           const float* __restrict__ Wk, const float* __restrict__ Wv,
           u16* __restrict__ Xh, u16* __restrict__ Xl,
           u16* __restrict__ Qth, u16* __restrict__ Qtl,
           u16* __restrict__ Kth, u16* __restrict__ Ktl,
           u16* __restrict__ Vth)
{
    const int bx = blockIdx.x;
    if (bx < 2048) {                       // xsplit: 8 elems/thread
        int i = (bx * 256 + threadIdx.x) * 8;
#pragma unroll
        for (int half = 0; half < 2; ++half) {
            float4 v = *(const float4*)(X + i + half * 4);
            ushort4 hi, lo;
            hi.x = f2bf(v.x); lo.x = f2bf(v.x - bf2f(hi.x));
            hi.y = f2bf(v.y); lo.y = f2bf(v.y - bf2f(hi.y));
            hi.z = f2bf(v.z); lo.z = f2bf(v.z - bf2f(hi.z));
            hi.w = f2bf(v.w); lo.w = f2bf(v.w - bf2f(hi.w));
            *(ushort4*)(Xh + i + half * 4) = hi;
            *(ushort4*)(Xl + i + half * 4) = lo;
        }
    } else if (bx < 3072) {                // wtrans hi/lo: [16][1024][64] -> [h*64+d][e]
        const int f = bx - 2048;           // 0..1023
        const int z = f >> 9, y = (f >> 5) & 15, x = f & 31;
        const float* W  = z ? Wk  : Wq;
        u16* Oh         = z ? Kth : Qth;
        u16* Ol         = z ? Ktl : Qtl;
        const int d  = threadIdx.x & 63;
        const int e0 = (x * 4 + (threadIdx.x >> 6)) * 8;
        const float* src = W + ((size_t)y * EMB + e0) * HDIM + d;
        ushort4 h0, h1, l0, l1;
        float v; u16 hv;
        v = src[0 * 64]; hv = f2bf(v); h0.x = hv; l0.x = f2bf(v - bf2f(hv));
        v = src[1 * 64]; hv = f2bf(v); h0.y = hv; l0.y = f2bf(v - bf2f(hv));
        v = src[2 * 64]; hv = f2bf(v); h0.z = hv; l0.z = f2bf(v - bf2f(hv));
        v = src[3 * 64]; hv = f2bf(v); h0.w = hv; l0.w = f2bf(v - bf2f(hv));
        v = src[4 * 64]; hv = f2bf(v); h1.x = hv; l1.x = f2bf(v - bf2f(hv));
        v = src[5 * 64]; hv = f2bf(v); h1.y = hv; l1.y = f2bf(v - bf2f(hv));
        v = src[6 * 64]; hv = f2bf(v); h1.z = hv; l1.z = f2bf(v - bf2f(hv));
        v = src[7 * 64]; hv = f2bf(v); h1.w = hv; l1.w = f2bf(v - bf2f(hv));
        size_t obase = ((size_t)y * HDIM + d) * EMB + e0;
        *(ushort4*)(Oh + obase)     = h0;
        *(ushort4*)(Oh + obase + 4) = h1;
        *(ushort4*)(Ol + obase)     = l0;
        *(ushort4*)(Ol + obase + 4) = l1;
    } else {                               // Wv transpose -> bf16 (1-pass precision)
        const int f = bx - 3072;           // 0..511
        const int y = f >> 5, x = f & 31;
        const int d  = threadIdx.x & 63;
        const int e0 = (x * 4 + (threadIdx.x >> 6)) * 8;
        const float* src = Wv + ((size_t)y * EMB + e0) * HDIM + d;
        ushort4 h0, h1;
        h0.x = f2bf(src[0 * 64]); h0.y = f2bf(src[1 * 64]);
        h0.z = f2bf(src[2 * 64]); h0.w = f2bf(src[3 * 64]);
        h1.x = f2bf(src[4 * 64]); h1.y = f2bf(src[5 * 64]);
        h1.z = f2bf(src[6 * 64]); h1.w = f2bf(src[7 * 64]);
        size_t obase = ((size_t)y * HDIM + d) * EMB + e0;
        *(ushort4*)(Vth + obase)     = h0;
        *(ushort4*)(Vth + obase + 4) = h1;
    }
}

// ---------------------------------------------------------------------------
// Kernel 1 (fused): Q/K/V projections.  (unchanged)
// ---------------------------------------------------------------------------
__global__ __launch_bounds__(256, 2)
void qkv_fused(const u16* __restrict__ Xh, const u16* __restrict__ Xl,
               const u16* __restrict__ Wqh, const u16* __restrict__ Wql,
               const u16* __restrict__ Wkh, const u16* __restrict__ Wkl,
               const u16* __restrict__ Wvt,
               u16* __restrict__ Qh, u16* __restrict__ Ql,
               u16* __restrict__ Kh, u16* __restrict__ Kl,
               u16* __restrict__ Vt)
{
    const int z  = blockIdx.z;
    const bool isV = (z == 2);
    const int m0 = blockIdx.x * 128;
    const int n0 = blockIdx.y * 128;
    const int t    = threadIdx.x;
    const int wave = t >> 6, lane = t & 63;
    const int wm = wave & 1, wn = wave >> 1;
    const int l16 = lane & 15, quad = lane >> 4;

    __shared__ u16 Ahs[128][STR];
    __shared__ u16 Als[128][STR];
    __shared__ u16 Bhs[128][STR];
    __shared__ u16 Bls[128][STR];

    const u16* Bh_g = isV ? Wvt : (z ? Wkh : Wqh);
    const u16* Bl_g = z ? Wkl : Wql;            // unused when isV

    const int ar0 = t >> 2, ak = (t & 3) * 8, ar1 = ar0 + 64;

    f32x4 acc[4][4];
#pragma unroll
    for (int i = 0; i < 4; ++i)
#pragma unroll
        for (int j = 0; j < 4; ++j) acc[i][j] = (f32x4){0.f, 0.f, 0.f, 0.f};

    bf16x8 cur[8], nxt[8], nx2[8];
#define QK_LOAD(dst, kk)                                                            \
    do {                                                                            \
        dst[0] = *(const bf16x8*)(Xh  + (size_t)(m0 + ar0) * EMB + (kk) + ak);      \
        dst[1] = *(const bf16x8*)(Xh  + (size_t)(m0 + ar1) * EMB + (kk) + ak);      \
        dst[4] = *(const bf16x8*)(Bh_g + (size_t)(n0 + ar0) * EMB + (kk) + ak);     \
        dst[5] = *(const bf16x8*)(Bh_g + (size_t)(n0 + ar1) * EMB + (kk) + ak);     \
        if (!isV) {                                                                 \
            dst[2] = *(const bf16x8*)(Xl  + (size_t)(m0 + ar0) * EMB + (kk) + ak);  \
            dst[3] = *(const bf16x8*)(Xl  + (size_t)(m0 + ar1) * EMB + (kk) + ak);  \
            dst[6] = *(const bf16x8*)(Bl_g + (size_t)(n0 + ar0) * EMB + (kk) + ak); \
            dst[7] = *(const bf16x8*)(Bl_g + (size_t)(n0 + ar1) * EMB + (kk) + ak); \
        }                                                                           \
    } while (0)

    QK_LOAD(cur, 0);
    QK_LOAD(nxt, 32);

    for (int k0 = 0; k0 < EMB; k0 += 32) {
        __syncthreads();
        *(bf16x8*)&Ahs[ar0][ak] = cur[0];  *(bf16x8*)&Ahs[ar1][ak] = cur[1];
        *(bf16x8*)&Bhs[ar0][ak] = cur[4];  *(bf16x8*)&Bhs[ar1][ak] = cur[5];
        if (!isV) {
            *(bf16x8*)&Als[ar0][ak] = cur[2];  *(bf16x8*)&Als[ar1][ak] = cur[3];
            *(bf16x8*)&Bls[ar0][ak] = cur[6];  *(bf16x8*)&Bls[ar1][ak] = cur[7];
        }
        __syncthreads();

        const int kn = (k0 + 64 < EMB) ? k0 + 64 : 0;   // dummy reload at end
        QK_LOAD(nx2, kn);

        bf16x8 B4h[4], B4l[4];
#pragma unroll
        for (int j = 0; j < 4; ++j) {
            B4h[j] = *(const bf16x8*)&Bhs[wn * 64 + 16 * j + l16][quad * 8];
            if (!isV)
                B4l[j] = *(const bf16x8*)&Bls[wn * 64 + 16 * j + l16][quad * 8];
        }
#pragma unroll
        for (int i = 0; i < 4; ++i) {
            bf16x8 Ai_h = *(const bf16x8*)&Ahs[wm * 64 + 16 * i + l16][quad * 8];
            if (!isV) {
                bf16x8 Ai_l = *(const bf16x8*)&Als[wm * 64 + 16 * i + l16][quad * 8];
#pragma unroll
                for (int j = 0; j < 4; ++j) {
                    acc[i][j] = __builtin_amdgcn_mfma_f32_16x16x32_bf16(Ai_h, B4h[j], acc[i][j], 0, 0, 0);
                    acc[i][j] = __builtin_amdgcn_mfma_f32_16x16x32_bf16(Ai_h, B4l[j], acc[i][j], 0, 0, 0);
                    acc[i][j] = __builtin_amdgcn_mfma_f32_16x16x32_bf16(Ai_l, B4h[j], acc[i][j], 0, 0, 0);
                }
            } else {
#pragma unroll
                for (int j = 0; j < 4; ++j)
                    acc[i][j] = __builtin_amdgcn_mfma_f32_16x16x32_bf16(Ai_h, B4h[j], acc[i][j], 0, 0, 0);
            }
        }
#pragma unroll
        for (int q = 0; q < 8; ++q) { cur[q] = nxt[q]; nxt[q] = nx2[q]; }
    }
#undef QK_LOAD

    const int b = m0 >> 11;
    const int h = (n0 + wn * 64) >> 6;
    if (isV) {
#pragma unroll
        for (int i = 0; i < 4; ++i)
#pragma unroll
            for (int j = 0; j < 4; ++j) {
                int d  = 16 * j + l16;
                int tt = (m0 & (SEQ - 1)) + wm * 64 + 16 * i + quad * 4;
                ushort4 o;
                o.x = f2bf(acc[i][j][0]); o.y = f2bf(acc[i][j][1]);
                o.z = f2bf(acc[i][j][2]); o.w = f2bf(acc[i][j][3]);
                *(ushort4*)(Vt + ((size_t)(b * HEADS + h) * HDIM + d) * SEQ + tt) = o;
            }
    } else {
        u16* Oh = z ? Kh : Qh;
        u16* Ol = z ? Kl : Ql;
        const float esc = z ? 1.0f : QSCALE;    // Q carries the softmax scale
#pragma unroll
        for (int i = 0; i < 4; ++i)
#pragma unroll
            for (int r = 0; r < 4; ++r) {
                int tt = (m0 & (SEQ - 1)) + wm * 64 + 16 * i + quad * 4 + r;
                size_t rowbase = ((size_t)(b * HEADS + h) * SEQ + tt) * HDIM;
#pragma unroll
                for (int j = 0; j < 4; ++j) {
                    int d = 16 * j + l16;
                    float v = acc[i][j][r] * esc;
                    u16 hv = f2bf(v);
                    Oh[rowbase + d] = hv;
                    Ol[rowbase + d] = f2bf(v - bf2f(hv));
                }
            }
    }
}

// ---------------------------------------------------------------------------
// Kernel 2: flash attention v5 -- NO LDS, NO BARRIERS in the loop.
//   R2-R4 all plateaued ~100us with no pipe >40%: LDS staging (barriers,
//   conflicts, staging VALU) was overhead for data that is L2-resident
//   (768 KB K/V per bh; XCD-grouped blocks pin 4 bh = 3 MB in one XCD L2).
//   Every MFMA operand is a lane-contiguous 16B global chunk -> load direct
//   to registers.  2q x 2k wave split (verified v4 algebra), wave-local
//   online softmax (defer-max THR=8), in-register P exchange (4 shfl),
//   single end-of-kernel cross-wave combine (17 KB LDS, one barrier).
// ---------------------------------------------------------------------------
__global__ __launch_bounds__(256, 3)
void attn_mfma(const u16* __restrict__ Qh, const u16* __restrict__ Ql,
               const u16* __restrict__ Kh, const u16* __restrict__ Kl,
               const u16* __restrict__ Vt, u16* __restrict__ Cb,
               const float* __restrict__ Wo, u16* __restrict__ Woh)
{
    const int w = blockIdx.x;
    if (w >= 1024) {                       // Wo -> bf16 strip (16 blocks)
        int base = ((w - 1024) * 256 + threadIdx.x) * 8;
#pragma unroll 4
        for (int it = 0; it < 32; ++it) {
#pragma unroll
            for (int half = 0; half < 2; ++half) {
                float4 v = *(const float4*)(Wo + base + half * 4);
                ushort4 o;
                o.x = f2bf(v.x); o.y = f2bf(v.y); o.z = f2bf(v.z); o.w = f2bf(v.w);
                *(ushort4*)(Woh + base + half * 4) = o;
            }
            base += 16 * 256 * 8;
        }
        return;
    }

    // decode: w = (bh&7) + 8*(qtile + 32*(bh>>3))  -> bh group shares XCD
    const int g     = w >> 3;
    const int qtile = g & 31;
    const int bh    = (w & 7) + ((g >> 5) << 3);

    const int t    = threadIdx.x;
    const int wave = t >> 6;
    const int lane = t & 63;
    const int l31  = lane & 31;
    const int hi   = lane >> 5;
    const int wq   = wave & 1;             // q-half
    const int wk   = wave >> 1;             // k-half

    __shared__ float fb[2 * 64 * 34];      // 17408 B, end-combine only

    const size_t bh_off = (size_t)bh * SEQ * HDIM;
    const u16* Qhb = Qh + bh_off;
    const u16* Qlb = Ql + bh_off;
    const u16* Khb = Kh + bh_off;
    const u16* Klb = Kl + bh_off;
    const u16* Vtb = Vt + bh_off;   // [64][SEQ]

    const int qb0 = qtile * 64 + wq * 32;

    // Q B-fragments (col q = qb0+l31, k-elems d = ks*16 + hi*8 + j)
    bf16x8 bQh[4], bQl[4];
#pragma unroll
    for (int ks = 0; ks < 4; ++ks) {
        const u16* pH = Qhb + (size_t)(qb0 + l31) * HDIM + ks * 16 + hi * 8;
        const u16* pL = Qlb + (size_t)(qb0 + l31) * HDIM + ks * 16 + hi * 8;
        bQh[ks] = *(const bf16x8*)pH;
        bQl[ks] = *(const bf16x8*)pL;
    }

    f32x16 accO0, accO1;
#pragma unroll
    for (int r = 0; r < 16; ++r) { accO0[r] = 0.f; accO1[r] = 0.f; }
    float m_i = -1e30f, l_i = 0.f;

    // direct-global fragment base pointers (all lane-contiguous 16B chunks)
    const u16* pKh = Khb + (size_t)(wk * 32 + l31) * HDIM + hi * 8;   // A: K row
    const u16* pKl = Klb + (size_t)(wk * 32 + l31) * HDIM + hi * 8;
    const u16* pV0 = Vtb + (size_t)l31 * SEQ        + (4 * wk + hi) * 8;  // A: V^T row d
    const u16* pV1 = Vtb + (size_t)(32 + l31) * SEQ + (4 * wk + hi) * 8;

    // preload K fragments for iter 0
    bf16x8 kh[4], kl[4];
#pragma unroll
    for (int ks = 0; ks < 4; ++ks) {
        kh[ks] = *(const bf16x8*)(pKh + ks * 16);
        kl[ks] = *(const bf16x8*)(pKl + ks * 16);
    }

    for (int it = 0; it < 32; ++it) {
        const int s0 = it * 64;

        // V loads for this iter (consumed at the bottom -> latency self-hides)
        bf16x8 v0[2], v1[2];
#pragma unroll
        for (int ks = 0; ks < 2; ++ks) {
            v0[ks] = *(const bf16x8*)(pV0 + s0 + ks * 16);
            v1[ks] = *(const bf16x8*)(pV1 + s0 + ks * 16);
        }

        // ---- S^T = K Q^T (3-pass split), wave's 32 k-rows ----
        f32x16 accS;
#pragma unroll
        for (int r = 0; r < 16; ++r) accS[r] = 0.f;
        __builtin_amdgcn_s_setprio(1);
#pragma unroll
        for (int ks = 0; ks < 4; ++ks) {
            accS = __builtin_amdgcn_mfma_f32_32x32x16_bf16(kh[ks], bQh[ks], accS, 0, 0, 0);
            accS = __builtin_amdgcn_mfma_f32_32x32x16_bf16(kl[ks], bQh[ks], accS, 0, 0, 0);
            accS = __builtin_amdgcn_mfma_f32_32x32x16_bf16(kh[ks], bQl[ks], accS, 0, 0, 0);
        }
        __builtin_amdgcn_s_setprio(0);

        // prefetch next iter's K in place (WAR after last consuming MFMA)
        {
            const int sn = (it < 31) ? s0 + 64 : 0;
            const u16* nKh = pKh + (size_t)sn * HDIM;
            const u16* nKl = pKl + (size_t)sn * HDIM;
#pragma unroll
            for (int ks = 0; ks < 4; ++ks) {
                kh[ks] = *(const bf16x8*)(nKh + ks * 16);
                kl[ks] = *(const bf16x8*)(nKl + ks * 16);
            }
        }

        // ---- wave-local online softmax (lane pair l, l^32 share q-col) ----
        float P[16];
        {
            float vmax = fmaxf(fmaxf(accS[0], accS[1]), fmaxf(accS[2], accS[3]));
#pragma unroll
            for (int r = 4; r < 16; r += 4)
                vmax = fmaxf(vmax, fmaxf(fmaxf(accS[r], accS[r + 1]),
                                         fmaxf(accS[r + 2], accS[r + 3])));
            vmax = fmaxf(vmax, __shfl_xor(vmax, 32, 64));
            if (!__all(vmax - m_i <= 8.0f)) {        // defer-max (T13)
                float mn = fmaxf(m_i, vmax);
                float alph = fast_exp2(m_i - mn);
                m_i = mn;
                l_i *= alph;
#pragma unroll
                for (int r = 0; r < 16; ++r) { accO0[r] *= alph; accO1[r] *= alph; }
            }
            float s = 0.f;
#pragma unroll
            for (int r = 0; r < 16; ++r) {
                P[r] = fast_exp2(accS[r] - m_i);
                s += P[r];
            }
            s += __shfl_xor(s, 32, 64);
            l_i += s;
        }

        // ---- P -> bf16 PV B-fragments, in-register (4 shfl) ----
        unsigned A_[4], B_[4];
#pragma unroll
        for (int rq = 0; rq < 4; ++rq) {
            A_[rq] = pk_trunc(P[4 * rq + 0], P[4 * rq + 1]);
            B_[rq] = pk_trunc(P[4 * rq + 2], P[4 * rq + 3]);
        }
        bf16x8 bP[2];
#pragma unroll
        for (int ks = 0; ks < 2; ++ks) {
            unsigned sndA = hi ? A_[2 * ks] : A_[2 * ks + 1];
            unsigned sndB = hi ? B_[2 * ks] : B_[2 * ks + 1];
            unsigned rcvA = __shfl_xor(sndA, 32, 64);
            unsigned rcvB = __shfl_xor(sndB, 32, 64);
            union { unsigned u[4]; bf16x8 v; } tmp;
            tmp.u[0] = hi ? rcvA : A_[2 * ks];
            tmp.u[1] = hi ? rcvB : B_[2 * ks];
            tmp.u[2] = hi ? A_[2 * ks + 1] : rcvA;
            tmp.u[3] = hi ? B_[2 * ks + 1] : rcvB;
            bP[ks] = tmp.v;
        }

        // ---- O^T += V^T P^T over wave's 32 s ----
        __builtin_amdgcn_s_setprio(1);
#pragma unroll
        for (int ks = 0; ks < 2; ++ks) {
            accO0 = __builtin_amdgcn_mfma_f32_32x32x16_bf16(v0[ks], bP[ks], accO0, 0, 0, 0);
            accO1 = __builtin_amdgcn_mfma_f32_32x32x16_bf16(v1[ks], bP[ks], accO1, 0, 0, 0);
        }
        __builtin_amdgcn_s_setprio(0);
    }

    // ---- cross-wave (wk) combine via LDS, once ----
    if (wk) {
        const int slot = ((wave - 2) * 64 + lane) * 34;
#pragma unroll
        for (int r = 0; r < 16; ++r) {
            fb[slot + r]      = accO0[r];
            fb[slot + 16 + r] = accO1[r];
        }
        fb[slot + 32] = m_i;
        fb[slot + 33] = l_i;
    }
    __syncthreads();
    if (!wk) {
        const int ps = ((wave + 2 - 2) * 64 + lane) * 34;   // partner wave+2 -> slot (wave)*64
        const float m1 = fb[ps + 32], l1 = fb[ps + 33];
        const float mS = fmaxf(m_i, m1);
        float f0 = fast_exp2(m_i - mS);
        float f1 = fast_exp2(m1 - mS);
        const float inv = 1.f / (l_i * f0 + l1 * f1);
        f0 *= inv; f1 *= inv;
        const int b = bh >> 4, h = bh & 15;
        u16* crow = Cb + ((size_t)b * SEQ + qb0 + l31) * EMB + h * HDIM;
#pragma unroll
        for (int rq = 0; rq < 4; ++rq) {
            ushort4 o;
            o.x = f2bf(accO0[4 * rq + 0] * f0 + fb[ps + 4 * rq + 0] * f1);
            o.y = f2bf(accO0[4 * rq + 1] * f0 + fb[ps + 4 * rq + 1] * f1);
            o.z = f2bf(accO0[4 * rq + 2] * f0 + fb[ps + 4 * rq + 2] * f1);
            o.w = f2bf(accO0[4 * rq + 3] * f0 + fb[ps + 4 * rq + 3] * f1);
            *(ushort4*)(crow + 8 * rq + 4 * hi) = o;
        }
#pragma unroll
        for (int rq = 0; rq < 4; ++rq) {
            ushort4 o;
            o.x = f2bf(accO1[4 * rq + 0] * f0 + fb[ps + 16 + 4 * rq + 0] * f1);
            o.y = f2bf(accO1[4 * rq + 1] * f0 + fb[ps + 16 + 4 * rq + 1] * f1);
            o.z = f2bf(accO1[4 * rq + 2] * f0 + fb[ps + 16 + 4 * rq + 2] * f1);
            o.w = f2bf(accO1[4 * rq + 3] * f0 + fb[ps + 16 + 4 * rq + 3] * f1);
            *(ushort4*)(crow + 32 + 8 * rq + 4 * hi) = o;
        }
    }
}

// ---------------------------------------------------------------------------
// Kernel 3: Y = X + C @ Wo^T, bf16 MFMA, 64x128 tiles, 2 blocks/CU.
// ---------------------------------------------------------------------------
__global__ __launch_bounds__(256, 2)
void oproj_mfma(const u16* __restrict__ Cb, const u16* __restrict__ Woh,
                const float* __restrict__ X, float* __restrict__ Y)
{
    const int m0 = blockIdx.x * 64;
    const int n0 = blockIdx.y * 128;
    const int t    = threadIdx.x;
    const int wave = t >> 6, lane = t & 63;
    const int wm = wave & 1, wn = wave >> 1;
    const int l16 = lane & 15, quad = lane >> 4;

    __shared__ u16 Ahs[64][STR];
    __shared__ u16 Bhs[128][STR];

    const int ar0 = t >> 2, ak = (t & 3) * 8, ar1 = ar0 + 64;

    f32x4 acc[2][4];
#pragma unroll
    for (int i = 0; i < 2; ++i)
#pragma unroll
        for (int j = 0; j < 4; ++j) acc[i][j] = (f32x4){0.f, 0.f, 0.f, 0.f};

    bf16x8 cur[3], nxt[3], nx2[3];
#define O_LOAD(dst, kk)                                                         \
    do {                                                                        \
        dst[0] = *(const bf16x8*)(Cb  + (size_t)(m0 + ar0) * EMB + (kk) + ak);  \
        dst[1] = *(const bf16x8*)(Woh + (size_t)(n0 + ar0) * EMB + (kk) + ak);  \
        dst[2] = *(const bf16x8*)(Woh + (size_t)(n0 + ar1) * EMB + (kk) + ak);  \
    } while (0)

    O_LOAD(cur, 0);
    O_LOAD(nxt, 32);

    for (int k0 = 0; k0 < EMB; k0 += 32) {
        __syncthreads();
        *(bf16x8*)&Ahs[ar0][ak] = cur[0];
        *(bf16x8*)&Bhs[ar0][ak] = cur[1];  *(bf16x8*)&Bhs[ar1][ak] = cur[2];
        __syncthreads();

        const int kn = (k0 + 64 < EMB) ? k0 + 64 : 0;
        O_LOAD(nx2, kn);

        bf16x8 B4[4];
#pragma unroll
        for (int j = 0; j < 4; ++j)
            B4[j] = *(const bf16x8*)&Bhs[wn * 64 + 16 * j + l16][quad * 8];
#pragma unroll
        for (int i = 0; i < 2; ++i) {
            bf16x8 Ai = *(const bf16x8*)&Ahs[wm * 32 + 16 * i + l16][quad * 8];
#pragma unroll
            for (int j = 0; j < 4; ++j)
                acc[i][j] = __builtin_amdgcn_mfma_f32_16x16x32_bf16(Ai, B4[j], acc[i][j], 0, 0, 0);
        }
#pragma unroll
        for (int q = 0; q < 3; ++q) { cur[q] = nxt[q]; nxt[q] = nx2[q]; }
    }
#undef O_LOAD

#pragma unroll
    for (int i = 0; i < 2; ++i)
#pragma unroll
        for (int r = 0; r < 4; ++r) {
            int m = m0 + wm * 32 + 16 * i + quad * 4 + r;
#pragma unroll
            for (int j = 0; j < 4; ++j) {
                int n = n0 + wn * 64 + 16 * j + l16;
                Y[(size_t)m * EMB + n] = acc[i][j][r] + X[(size_t)m * EMB + n];
            }
        }
}

// ---------------------------------------------------------------------------
// Workspace map (u16 units, 32M total = 64 MiB):
//   [0]   Qh 4M   [4M] Ql   [8M] Kh   [12M] Kl   [16M] Vt
//   [20M] Xh 4M   (-> Cb after qkv_fused)
//   [24M] Xl 4M   (-> Woh after qkv_fused, written by attn's strip)
//   [28M] Wtq_h 1M, Wtq_l, Wtk_h, Wtk_l
// Wvt (1M u16 = 2 MiB) lives in d_out scratch (16 MiB, dead until oproj).
// ---------------------------------------------------------------------------
extern "C" void kernel_launch(void* const* d_in, const int* in_sizes, int n_in,
                              void* d_out, int out_size, void* d_ws,
                              size_t ws_size, hipStream_t stream)
{
    const float* x  = (const float*)d_in[0];
    const float* Wq = (const float*)d_in[1];
    const float* Wk = (const float*)d_in[2];
    const float* Wv = (const float*)d_in[3];
    const float* Wo = (const float*)d_in[4];
    float* Y = (float*)d_out;

    const size_t NPER = (size_t)MROWS * EMB;   // 4,194,304
    u16* base  = (u16*)d_ws;
    u16* Qh    = base;
    u16* Ql    = Qh + NPER;
    u16* Kh    = Ql + NPER;
    u16* Kl    = Kh + NPER;
    u16* Vt    = Kl + NPER;
    u16* Xh    = Vt + NPER;
    u16* Xl    = Xh + NPER;
    u16* Wtq_h = Xl + NPER;
    u16* Wtq_l = Wtq_h + EMB * EMB;
    u16* Wtk_h = Wtq_l + EMB * EMB;
    u16* Wtk_l = Wtk_h + EMB * EMB;
    u16* Wvt   = (u16*)d_out;   // scratch in output buffer (dead until oproj)
    u16* Cb    = Xh;            // alias: Xh dead after qkv_fused
    u16* Woh   = Xl;            // alias: Xl dead after qkv_fused

    prep1<<<dim3(3584), 256, 0, stream>>>(x, Wq, Wk, Wv, Xh, Xl,
                                          Wtq_h, Wtq_l, Wtk_h, Wtk_l, Wvt);
    qkv_fused<<<dim3(32, 8, 3), 256, 0, stream>>>(Xh, Xl, Wtq_h, Wtq_l,
                                                  Wtk_h, Wtk_l, Wvt,
                                                  Qh, Ql, Kh, Kl, Vt);
    attn_mfma<<<dim3(1040), 256, 0, stream>>>(Qh, Ql, Kh, Kl, Vt, Cb, Wo, Woh);
    oproj_mfma<<<dim3(64, 8), 256, 0, stream>>>(Cb, Woh, x, Y);
}

// Round 9
// 253.031 us; speedup vs baseline: 1.4598x; 1.4598x over previous
//
#include <hip/hip_runtime.h>

#define EMB   1024
#define HEADS 16
#define HDIM  64
#define BATCH 2
#define SEQ   2048
#define MROWS (BATCH*SEQ)   // 4096
#define STR   40            // oproj LDS k-stride in u16: 80 B
#define QSCALE 0.1803368801111204f   // 0.125 * log2(e): Q pre-scale -> exp2 softmax

typedef __attribute__((ext_vector_type(8))) short bf16x8;   // 8 bf16 (4 VGPRs)
typedef __attribute__((ext_vector_type(4))) float f32x4;    // 16x16 MFMA C/D
typedef unsigned short u16;

__device__ __forceinline__ u16 f2bf(float f) {              // round-to-nearest-even
    unsigned u = __float_as_uint(f);
    u += 0x7fffu + ((u >> 16) & 1u);
    return (u16)(u >> 16);
}
__device__ __forceinline__ float bf2f(u16 h) {
    return __uint_as_float((unsigned)h << 16);
}
__device__ __forceinline__ float fast_exp2(float x) {
#if __has_builtin(__builtin_amdgcn_exp2f)
    return __builtin_amdgcn_exp2f(x);
#else
    return __expf(x * 0.6931471805599453f);
#endif
}
// pack two floats -> two truncated bf16 in one v_perm_b32 (lo in [15:0])
__device__ __forceinline__ unsigned pk_trunc(float lo, float hi) {
    return __builtin_amdgcn_perm(__float_as_uint(hi), __float_as_uint(lo),
                                 0x07060302u);
}
// async global->LDS, 16B per lane (dest = wave-uniform base + lane*16)
__device__ __forceinline__ void gload16(const u16* g, u16* l) {
    __builtin_amdgcn_global_load_lds(
        (const __attribute__((address_space(1))) unsigned int*)g,
        (__attribute__((address_space(3))) unsigned int*)l, 16, 0, 0);
}

// XOR-swizzled LDS offset (u16 units): 64-u16 rows, 8-u16 chunks, chunk^=row&7.
#define SWZ(r, ch) ((((r) << 6)) + ((((ch) ^ ((r) & 7))) << 3))

// ---------------------------------------------------------------------------
// prep1: fused  [bx<2048] X->Xh/Xl split | [bx<3072] Wq/Wk transpose+hi/lo
//        | [else] Wv transpose->bf16 (Wvt lives in d_out scratch).
// ---------------------------------------------------------------------------
__global__ __launch_bounds__(256)
void prep1(const float* __restrict__ X, const float* __restrict__ Wq,
           const float* __restrict__ Wk, const float* __restrict__ Wv,
           u16* __restrict__ Xh, u16* __restrict__ Xl,
           u16* __restrict__ Qth, u16* __restrict__ Qtl,
           u16* __restrict__ Kth, u16* __restrict__ Ktl,
           u16* __restrict__ Vth)
{
    const int bx = blockIdx.x;
    if (bx < 2048) {                       // xsplit: 8 elems/thread
        int i = (bx * 256 + threadIdx.x) * 8;
#pragma unroll
        for (int half = 0; half < 2; ++half) {
            float4 v = *(const float4*)(X + i + half * 4);
            ushort4 hi, lo;
            hi.x = f2bf(v.x); lo.x = f2bf(v.x - bf2f(hi.x));
            hi.y = f2bf(v.y); lo.y = f2bf(v.y - bf2f(hi.y));
            hi.z = f2bf(v.z); lo.z = f2bf(v.z - bf2f(hi.z));
            hi.w = f2bf(v.w); lo.w = f2bf(v.w - bf2f(hi.w));
            *(ushort4*)(Xh + i + half * 4) = hi;
            *(ushort4*)(Xl + i + half * 4) = lo;
        }
    } else if (bx < 3072) {                // wtrans hi/lo: [16][1024][64] -> [h*64+d][e]
        const int f = bx - 2048;           // 0..1023
        const int z = f >> 9, y = (f >> 5) & 15, x = f & 31;
        const float* W  = z ? Wk  : Wq;
        u16* Oh         = z ? Kth : Qth;
        u16* Ol         = z ? Ktl : Qtl;
        const int d  = threadIdx.x & 63;
        const int e0 = (x * 4 + (threadIdx.x >> 6)) * 8;
        const float* src = W + ((size_t)y * EMB + e0) * HDIM + d;
        ushort4 h0, h1, l0, l1;
        float v; u16 hv;
        v = src[0 * 64]; hv = f2bf(v); h0.x = hv; l0.x = f2bf(v - bf2f(hv));
        v = src[1 * 64]; hv = f2bf(v); h0.y = hv; l0.y = f2bf(v - bf2f(hv));
        v = src[2 * 64]; hv = f2bf(v); h0.z = hv; l0.z = f2bf(v - bf2f(hv));
        v = src[3 * 64]; hv = f2bf(v); h0.w = hv; l0.w = f2bf(v - bf2f(hv));
        v = src[4 * 64]; hv = f2bf(v); h1.x = hv; l1.x = f2bf(v - bf2f(hv));
        v = src[5 * 64]; hv = f2bf(v); h1.y = hv; l1.y = f2bf(v - bf2f(hv));
        v = src[6 * 64]; hv = f2bf(v); h1.z = hv; l1.z = f2bf(v - bf2f(hv));
        v = src[7 * 64]; hv = f2bf(v); h1.w = hv; l1.w = f2bf(v - bf2f(hv));
        size_t obase = ((size_t)y * HDIM + d) * EMB + e0;
        *(ushort4*)(Oh + obase)     = h0;
        *(ushort4*)(Oh + obase + 4) = h1;
        *(ushort4*)(Ol + obase)     = l0;
        *(ushort4*)(Ol + obase + 4) = l1;
    } else {                               // Wv transpose -> bf16 (1-pass precision)
        const int f = bx - 3072;           // 0..511
        const int y = f >> 5, x = f & 31;
        const int d  = threadIdx.x & 63;
        const int e0 = (x * 4 + (threadIdx.x >> 6)) * 8;
        const float* src = Wv + ((size_t)y * EMB + e0) * HDIM + d;
        ushort4 h0, h1;
        h0.x = f2bf(src[0 * 64]); h0.y = f2bf(src[1 * 64]);
        h0.z = f2bf(src[2 * 64]); h0.w = f2bf(src[3 * 64]);
        h1.x = f2bf(src[4 * 64]); h1.y = f2bf(src[5 * 64]);
        h1.z = f2bf(src[6 * 64]); h1.w = f2bf(src[7 * 64]);
        size_t obase = ((size_t)y * HDIM + d) * EMB + e0;
        *(ushort4*)(Vth + obase)     = h0;
        *(ushort4*)(Vth + obase + 4) = h1;
    }
}

// ---------------------------------------------------------------------------
// Kernel 1 (fused): Q/K/V projections, global_load_lds staging (m151: +35%
// over reg-staged at 128-tile).  Linear LDS [128][32] per tile (conflict-free
// at the b128 floor for this fragment pattern), double-buffered, one barrier
// per K-step, stage-before-compute.  MFMA sequence identical -> bit-same.
// ---------------------------------------------------------------------------
__global__ __launch_bounds__(256, 2)
void qkv_fused(const u16* __restrict__ Xh, const u16* __restrict__ Xl,
               const u16* __restrict__ Wqh, const u16* __restrict__ Wql,
               const u16* __restrict__ Wkh, const u16* __restrict__ Wkl,
               const u16* __restrict__ Wvt,
               u16* __restrict__ Qh, u16* __restrict__ Ql,
               u16* __restrict__ Kh, u16* __restrict__ Kl,
               u16* __restrict__ Vt)
{
    const int z  = blockIdx.z;
    const bool isV = (z == 2);
    const int m0 = blockIdx.x * 128;
    const int n0 = blockIdx.y * 128;
    const int t    = threadIdx.x;
    const int wave = t >> 6, lane = t & 63;
    const int wm = wave & 1, wn = wave >> 1;
    const int l16 = lane & 15, quad = lane >> 4;

    // 2 bufs x {Ah,Al,Bh,Bl}[128][32] u16 = 64 KB
    __shared__ u16 lds[2 * 4 * 4096];

    const u16* Bh_g = isV ? Wvt : (z ? Wkh : Wqh);
    const u16* Bl_g = z ? Wkl : Wql;            // unused when isV

    // staging: wave w covers rows [w*32, w*32+32) of each tile in 2 calls;
    // lane l -> row += l>>2, col (l&3)*8 (16B), matching gload16's lane*16B.
    const int srow = wave * 32 + (lane >> 2);
    const int scol = (lane & 3) * 8;

    f32x4 acc[4][4];
#pragma unroll
    for (int i = 0; i < 4; ++i)
#pragma unroll
        for (int j = 0; j < 4; ++j) acc[i][j] = (f32x4){0.f, 0.f, 0.f, 0.f};

#define STAGE(buf, kk)                                                             \
    do {                                                                           \
        u16* Lb = &lds[(buf) * 16384];                                             \
        u16* Ld0 = Lb + (wave * 32) * 32;                                          \
        u16* Ld1 = Lb + (wave * 32 + 16) * 32;                                     \
        gload16(Xh   + (size_t)(m0 + srow) * EMB + (kk) + scol,      Ld0);         \
        gload16(Xh   + (size_t)(m0 + srow + 16) * EMB + (kk) + scol, Ld1);         \
        gload16(Bh_g + (size_t)(n0 + srow) * EMB + (kk) + scol,      Ld0 + 8192);  \
        gload16(Bh_g + (size_t)(n0 + srow + 16) * EMB + (kk) + scol, Ld1 + 8192);  \
        if (!isV) {                                                                \
            gload16(Xl   + (size_t)(m0 + srow) * EMB + (kk) + scol,      Ld0 + 4096); \
            gload16(Xl   + (size_t)(m0 + srow + 16) * EMB + (kk) + scol, Ld1 + 4096); \
            gload16(Bl_g + (size_t)(n0 + srow) * EMB + (kk) + scol,      Ld0 + 12288); \
            gload16(Bl_g + (size_t)(n0 + srow + 16) * EMB + (kk) + scol, Ld1 + 12288); \
        }                                                                          \
    } while (0)

    STAGE(0, 0);
    __syncthreads();

    for (int k0 = 0; k0 < EMB; k0 += 32) {
        const int cur = (k0 >> 5) & 1;
        if (k0 + 32 < EMB) STAGE(cur ^ 1, k0 + 32);   // prefetch next K-tile

        const u16* Lb = &lds[cur * 16384];
        bf16x8 B4h[4], B4l[4];
#pragma unroll
        for (int j = 0; j < 4; ++j) {
            B4h[j] = *(const bf16x8*)(Lb + 8192 + (wn * 64 + 16 * j + l16) * 32 + quad * 8);
            if (!isV)
                B4l[j] = *(const bf16x8*)(Lb + 12288 + (wn * 64 + 16 * j + l16) * 32 + quad * 8);
        }
#pragma unroll
        for (int i = 0; i < 4; ++i) {
            bf16x8 Ai_h = *(const bf16x8*)(Lb + (wm * 64 + 16 * i + l16) * 32 + quad * 8);
            if (!isV) {
                bf16x8 Ai_l = *(const bf16x8*)(Lb + 4096 + (wm * 64 + 16 * i + l16) * 32 + quad * 8);
#pragma unroll
                for (int j = 0; j < 4; ++j) {
                    acc[i][j] = __builtin_amdgcn_mfma_f32_16x16x32_bf16(Ai_h, B4h[j], acc[i][j], 0, 0, 0);
                    acc[i][j] = __builtin_amdgcn_mfma_f32_16x16x32_bf16(Ai_h, B4l[j], acc[i][j], 0, 0, 0);
                    acc[i][j] = __builtin_amdgcn_mfma_f32_16x16x32_bf16(Ai_l, B4h[j], acc[i][j], 0, 0, 0);
                }
            } else {
#pragma unroll
                for (int j = 0; j < 4; ++j)
                    acc[i][j] = __builtin_amdgcn_mfma_f32_16x16x32_bf16(Ai_h, B4h[j], acc[i][j], 0, 0, 0);
            }
        }
        __syncthreads();   // drains prefetch (vmcnt0) + protects cur for reuse
    }
#undef STAGE

    const int b = m0 >> 11;
    const int h = (n0 + wn * 64) >> 6;
    if (isV) {
#pragma unroll
        for (int i = 0; i < 4; ++i)
#pragma unroll
            for (int j = 0; j < 4; ++j) {
                int d  = 16 * j + l16;
                int tt = (m0 & (SEQ - 1)) + wm * 64 + 16 * i + quad * 4;
                ushort4 o;
                o.x = f2bf(acc[i][j][0]); o.y = f2bf(acc[i][j][1]);
                o.z = f2bf(acc[i][j][2]); o.w = f2bf(acc[i][j][3]);
                *(ushort4*)(Vt + ((size_t)(b * HEADS + h) * HDIM + d) * SEQ + tt) = o;
            }
    } else {
        u16* Oh = z ? Kh : Qh;
        u16* Ol = z ? Kl : Ql;
        const float esc = z ? 1.0f : QSCALE;    // Q carries the softmax scale
#pragma unroll
        for (int i = 0; i < 4; ++i)
#pragma unroll
            for (int r = 0; r < 4; ++r) {
                int tt = (m0 & (SEQ - 1)) + wm * 64 + 16 * i + quad * 4 + r;
                size_t rowbase = ((size_t)(b * HEADS + h) * SEQ + tt) * HDIM;
#pragma unroll
                for (int j = 0; j < 4; ++j) {
                    int d = 16 * j + l16;
                    float v = acc[i][j][r] * esc;
                    u16 hv = f2bf(v);
                    Oh[rowbase + d] = hv;
                    Ol[rowbase + d] = f2bf(v - bf2f(hv));
                }
            }
    }
}

// ---------------------------------------------------------------------------
// Kernel 2: flash attention (R2's measured-best variant: 95 us).
// QBLK=64 (16 q-rows/wave), KVBLK=64, 16x16 MFMA, XCD-grouped 1D grid,
// 4 blocks/CU (32 KB LDS), setprio around MFMA clusters.
// ---------------------------------------------------------------------------
__global__ __launch_bounds__(256, 4)
void attn_mfma(const u16* __restrict__ Qh, const u16* __restrict__ Ql,
               const u16* __restrict__ Kh, const u16* __restrict__ Kl,
               const u16* __restrict__ Vt, u16* __restrict__ Cb,
               const float* __restrict__ Wo, u16* __restrict__ Woh)
{
    const int w = blockIdx.x;
    if (w >= 1024) {                       // Wo -> bf16 strip (16 blocks)
        int base = ((w - 1024) * 256 + threadIdx.x) * 8;
#pragma unroll 4
        for (int it = 0; it < 32; ++it) {
#pragma unroll
            for (int half = 0; half < 2; ++half) {
                float4 v = *(const float4*)(Wo + base + half * 4);
                ushort4 o;
                o.x = f2bf(v.x); o.y = f2bf(v.y); o.z = f2bf(v.z); o.w = f2bf(v.w);
                *(ushort4*)(Woh + base + half * 4) = o;
            }
            base += 16 * 256 * 8;
        }
        return;
    }

    // decode: w = (bh&7) + 8*(qtile + 32*(bh>>3))
    const int g    = w >> 3;
    const int qt0  = (g & 31) * 64;
    const int bh   = (w & 7) + ((g >> 5) << 3);

    const int t    = threadIdx.x;
    const int wave = t >> 6;
    const int lane = t & 63;
    const int l16  = lane & 15;
    const int quad = lane >> 4;

    __shared__ u16 Ksh[4096];   // K hi [s:64][d:64], swizzled
    __shared__ u16 Ksl[4096];   // K lo
    __shared__ u16 Vs [4096];   // V^T  [d:64][s:64], swizzled
    __shared__ u16 Ps [4096];   // P    [q:64][s:64], swizzled

    const size_t bh_off = (size_t)bh * SEQ * HDIM;
    const u16* Qhb = Qh + bh_off;
    const u16* Qlb = Ql + bh_off;
    const u16* Khb = Kh + bh_off;
    const u16* Klb = Kl + bh_off;
    const u16* Vtb = Vt + bh_off;   // [64][SEQ]

    // Q fragments: this wave's 16 q-rows
    const int qrow = qt0 + wave * 16 + l16;
    bf16x8 aQh[2], aQl[2];
    {
        const u16* bH = Qhb + (size_t)qrow * HDIM + quad * 8;
        const u16* bL = Qlb + (size_t)qrow * HDIM + quad * 8;
        aQh[0] = *(const bf16x8*)(bH);
        aQh[1] = *(const bf16x8*)(bH + 32);
        aQl[0] = *(const bf16x8*)(bL);
        aQl[1] = *(const bf16x8*)(bL + 32);
    }

    f32x4 accO[4];
    float m_i = -1e30f, l_i = 0.f;
#pragma unroll
    for (int j = 0; j < 4; ++j) accO[j] = (f32x4){0.f, 0.f, 0.f, 0.f};

    const int sr0 = t >> 3, sch = t & 7, sr1 = sr0 + 32;
    const int gc  = sch * 8;
    const int so0 = SWZ(sr0, sch), so1 = SWZ(sr1, sch);

    bf16x8 cur[6], nxt[6];
#define KV_LOAD(dst, ss)                                                       \
    do {                                                                       \
        dst[0] = *(const bf16x8*)(Khb + (size_t)((ss) + sr0) * HDIM + gc);     \
        dst[1] = *(const bf16x8*)(Khb + (size_t)((ss) + sr1) * HDIM + gc);     \
        dst[2] = *(const bf16x8*)(Klb + (size_t)((ss) + sr0) * HDIM + gc);     \
        dst[3] = *(const bf16x8*)(Klb + (size_t)((ss) + sr1) * HDIM + gc);     \
        dst[4] = *(const bf16x8*)(Vtb + (size_t)sr0 * SEQ + (ss) + gc);        \
        dst[5] = *(const bf16x8*)(Vtb + (size_t)sr1 * SEQ + (ss) + gc);        \
    } while (0)

    KV_LOAD(cur, 0);

    for (int s0 = 0; s0 < SEQ; s0 += 64) {
        __syncthreads();
        *(bf16x8*)&Ksh[so0] = cur[0];  *(bf16x8*)&Ksh[so1] = cur[1];
        *(bf16x8*)&Ksl[so0] = cur[2];  *(bf16x8*)&Ksl[so1] = cur[3];
        *(bf16x8*)&Vs [so0] = cur[4];  *(bf16x8*)&Vs [so1] = cur[5];
        __syncthreads();

        const int sn = (s0 + 64 < SEQ) ? s0 + 64 : 0;
        KV_LOAD(nxt, sn);

        // ---- S^T = K Q^T (3-pass split) ----
        f32x4 accS[4];
#pragma unroll
        for (int i = 0; i < 4; ++i) accS[i] = (f32x4){0.f, 0.f, 0.f, 0.f};
        __builtin_amdgcn_s_setprio(1);
#pragma unroll
        for (int c = 0; c < 2; ++c) {
#pragma unroll
            for (int i = 0; i < 4; ++i) {
                bf16x8 kh_ = *(const bf16x8*)&Ksh[SWZ(16 * i + l16, 4 * c + quad)];
                bf16x8 kl_ = *(const bf16x8*)&Ksl[SWZ(16 * i + l16, 4 * c + quad)];
                accS[i] = __builtin_amdgcn_mfma_f32_16x16x32_bf16(kh_, aQh[c], accS[i], 0, 0, 0);
                accS[i] = __builtin_amdgcn_mfma_f32_16x16x32_bf16(kl_, aQh[c], accS[i], 0, 0, 0);
                accS[i] = __builtin_amdgcn_mfma_f32_16x16x32_bf16(kh_, aQl[c], accS[i], 0, 0, 0);
            }
        }
        __builtin_amdgcn_s_setprio(0);

        // ---- online softmax (lane owns q-row; 2 shfl) ----
        {
            float vmax = fmaxf(fmaxf(accS[0][0], accS[0][1]),
                               fmaxf(accS[0][2], accS[0][3]));
#pragma unroll
            for (int i = 1; i < 4; ++i)
                vmax = fmaxf(vmax, fmaxf(fmaxf(accS[i][0], accS[i][1]),
                                         fmaxf(accS[i][2], accS[i][3])));
            vmax = fmaxf(vmax, __shfl_xor(vmax, 16, 64));
            vmax = fmaxf(vmax, __shfl_xor(vmax, 32, 64));
            float mn   = fmaxf(m_i, vmax);
            float alph = fast_exp2(m_i - mn);
            m_i = mn;
            float P[4][4], s = 0.f;
#pragma unroll
            for (int i = 0; i < 4; ++i)
#pragma unroll
                for (int r = 0; r < 4; ++r) {
                    P[i][r] = fast_exp2(accS[i][r] - mn);
                    s += P[i][r];
                }
            s += __shfl_xor(s, 16, 64);
            s += __shfl_xor(s, 32, 64);
            l_i = l_i * alph + s;
#pragma unroll
            for (int j = 0; j < 4; ++j) accO[j] *= alph;

            const int prow = wave * 16 + l16;
#pragma unroll
            for (int i = 0; i < 4; ++i) {
                uint2 pv;
                pv.x = pk_trunc(P[i][0], P[i][1]);
                pv.y = pk_trunc(P[i][2], P[i][3]);
                *(uint2*)&Ps[SWZ(prow, 2 * i + (quad >> 1)) + ((quad & 1) << 2)] = pv;
            }
        }

        // ---- O^T += V^T P^T (intra-wave Ps reuse; no barrier needed) ----
        __builtin_amdgcn_s_setprio(1);
#pragma unroll
        for (int c = 0; c < 2; ++c) {
            bf16x8 bP = *(const bf16x8*)&Ps[SWZ(wave * 16 + l16, 4 * c + quad)];
#pragma unroll
            for (int j = 0; j < 4; ++j) {
                bf16x8 aV = *(const bf16x8*)&Vs[SWZ(16 * j + l16, 4 * c + quad)];
                accO[j] = __builtin_amdgcn_mfma_f32_16x16x32_bf16(aV, bP, accO[j], 0, 0, 0);
            }
        }
        __builtin_amdgcn_s_setprio(0);
#pragma unroll
        for (int q = 0; q < 6; ++q) cur[q] = nxt[q];
    }
#undef KV_LOAD

    const int b = bh >> 4, h = bh & 15;
    {
        const int row = qt0 + wave * 16 + l16;
        const float inv = 1.f / l_i;
#pragma unroll
        for (int j = 0; j < 4; ++j) {
            ushort4 o;
            o.x = f2bf(accO[j][0] * inv); o.y = f2bf(accO[j][1] * inv);
            o.z = f2bf(accO[j][2] * inv); o.w = f2bf(accO[j][3] * inv);
            *(ushort4*)&Cb[((size_t)b * SEQ + row) * EMB + h * HDIM + 16 * j + quad * 4] = o;
        }
    }
}

// ---------------------------------------------------------------------------
// Kernel 3: Y = X + C @ Wo^T, bf16 MFMA, 64x128 tiles, 2 blocks/CU.
// ---------------------------------------------------------------------------
__global__ __launch_bounds__(256, 2)
void oproj_mfma(const u16* __restrict__ Cb, const u16* __restrict__ Woh,
                const float* __restrict__ X, float* __restrict__ Y)
{
    const int m0 = blockIdx.x * 64;
    const int n0 = blockIdx.y * 128;
    const int t    = threadIdx.x;
    const int wave = t >> 6, lane = t & 63;
    const int wm = wave & 1, wn = wave >> 1;
    const int l16 = lane & 15, quad = lane >> 4;

    __shared__ u16 Ahs[64][STR];
    __shared__ u16 Bhs[128][STR];

    const int ar0 = t >> 2, ak = (t & 3) * 8, ar1 = ar0 + 64;

    f32x4 acc[2][4];
#pragma unroll
    for (int i = 0; i < 2; ++i)
#pragma unroll
        for (int j = 0; j < 4; ++j) acc[i][j] = (f32x4){0.f, 0.f, 0.f, 0.f};

    bf16x8 cur[3], nxt[3], nx2[3];
#define O_LOAD(dst, kk)                                                         \
    do {                                                                        \
        dst[0] = *(const bf16x8*)(Cb  + (size_t)(m0 + ar0) * EMB + (kk) + ak);  \
        dst[1] = *(const bf16x8*)(Woh + (size_t)(n0 + ar0) * EMB + (kk) + ak);  \
        dst[2] = *(const bf16x8*)(Woh + (size_t)(n0 + ar1) * EMB + (kk) + ak);  \
    } while (0)

    O_LOAD(cur, 0);
    O_LOAD(nxt, 32);

    for (int k0 = 0; k0 < EMB; k0 += 32) {
        __syncthreads();
        *(bf16x8*)&Ahs[ar0][ak] = cur[0];
        *(bf16x8*)&Bhs[ar0][ak] = cur[1];  *(bf16x8*)&Bhs[ar1][ak] = cur[2];
        __syncthreads();

        const int kn = (k0 + 64 < EMB) ? k0 + 64 : 0;
        O_LOAD(nx2, kn);

        bf16x8 B4[4];
#pragma unroll
        for (int j = 0; j < 4; ++j)
            B4[j] = *(const bf16x8*)&Bhs[wn * 64 + 16 * j + l16][quad * 8];
#pragma unroll
        for (int i = 0; i < 2; ++i) {
            bf16x8 Ai = *(const bf16x8*)&Ahs[wm * 32 + 16 * i + l16][quad * 8];
#pragma unroll
            for (int j = 0; j < 4; ++j)
                acc[i][j] = __builtin_amdgcn_mfma_f32_16x16x32_bf16(Ai, B4[j], acc[i][j], 0, 0, 0);
        }
#pragma unroll
        for (int q = 0; q < 3; ++q) { cur[q] = nxt[q]; nxt[q] = nx2[q]; }
    }
#undef O_LOAD

#pragma unroll
    for (int i = 0; i < 2; ++i)
#pragma unroll
        for (int r = 0; r < 4; ++r) {
            int m = m0 + wm * 32 + 16 * i + quad * 4 + r;
#pragma unroll
            for (int j = 0; j < 4; ++j) {
                int n = n0 + wn * 64 + 16 * j + l16;
                Y[(size_t)m * EMB + n] = acc[i][j][r] + X[(size_t)m * EMB + n];
            }
        }
}

// ---------------------------------------------------------------------------
// Workspace map (u16 units, 32M total = 64 MiB):
//   [0]   Qh 4M   [4M] Ql   [8M] Kh   [12M] Kl   [16M] Vt
//   [20M] Xh 4M   (-> Cb after qkv_fused)
//   [24M] Xl 4M   (-> Woh after qkv_fused, written by attn's strip)
//   [28M] Wtq_h 1M, Wtq_l, Wtk_h, Wtk_l
// Wvt (1M u16 = 2 MiB) lives in d_out scratch (16 MiB, dead until oproj).
// ---------------------------------------------------------------------------
extern "C" void kernel_launch(void* const* d_in, const int* in_sizes, int n_in,
                              void* d_out, int out_size, void* d_ws,
                              size_t ws_size, hipStream_t stream)
{
    const float* x  = (const float*)d_in[0];
    const float* Wq = (const float*)d_in[1];
    const float* Wk = (const float*)d_in[2];
    const float* Wv = (const float*)d_in[3];
    const float* Wo = (const float*)d_in[4];
    float* Y = (float*)d_out;

    const size_t NPER = (size_t)MROWS * EMB;   // 4,194,304
    u16* base  = (u16*)d_ws;
    u16* Qh    = base;
    u16* Ql    = Qh + NPER;
    u16* Kh    = Ql + NPER;
    u16* Kl    = Kh + NPER;
    u16* Vt    = Kl + NPER;
    u16* Xh    = Vt + NPER;
    u16* Xl    = Xh + NPER;
    u16* Wtq_h = Xl + NPER;
    u16* Wtq_l = Wtq_h + EMB * EMB;
    u16* Wtk_h = Wtq_l + EMB * EMB;
    u16* Wtk_l = Wtk_h + EMB * EMB;
    u16* Wvt   = (u16*)d_out;   // scratch in output buffer (dead until oproj)
    u16* Cb    = Xh;            // alias: Xh dead after qkv_fused
    u16* Woh   = Xl;            // alias: Xl dead after qkv_fused

    prep1<<<dim3(3584), 256, 0, stream>>>(x, Wq, Wk, Wv, Xh, Xl,
                                          Wtq_h, Wtq_l, Wtk_h, Wtk_l, Wvt);
    qkv_fused<<<dim3(32, 8, 3), 256, 0, stream>>>(Xh, Xl, Wtq_h, Wtq_l,
                                                  Wtk_h, Wtk_l, Wvt,
                                                  Qh, Ql, Kh, Kl, Vt);
    attn_mfma<<<dim3(1040), 256, 0, stream>>>(Qh, Ql, Kh, Kl, Vt, Cb, Wo, Woh);
    oproj_mfma<<<dim3(64, 8), 256, 0, stream>>>(Cb, Woh, x, Y);
}